// Round 1
// baseline (674.363 us; speedup 1.0000x reference)
//
#include <hip/hip_runtime.h>
#include <hip/hip_bf16.h>

#define B_ 1024
#define L_ 2048
#define C_ 32
#define O_ 2048

typedef short bf16x8 __attribute__((ext_vector_type(8)));
typedef float f32x4 __attribute__((ext_vector_type(4)));

__device__ __forceinline__ unsigned short f2bf(float f) {
    union { float f; unsigned int u; } v; v.f = f;
    unsigned int r = v.u + (0x7fffu + ((v.u >> 16) & 1u));
    return (unsigned short)(r >> 16);
}

__device__ __forceinline__ void async16(const void* g, const void* l) {
    __builtin_amdgcn_global_load_lds(
        (const __attribute__((address_space(1))) unsigned int*)g,
        (__attribute__((address_space(3))) unsigned int*)l, 16, 0, 0);
}

// ---------------- pre-pass 1: x (B,L,C) fp32 -> xT (B,C,L) bf16 ----------------
__global__ __launch_bounds__(256) void k_transpose_x(const float* __restrict__ x,
                                                     unsigned short* __restrict__ xT) {
    __shared__ float tile[256 * 33];              // [l][c], pitch 33 breaks conflicts
    const int b  = blockIdx.x >> 3;
    const int l0 = (blockIdx.x & 7) << 8;         // 256-l chunk
    const int t  = threadIdx.x;
    const float* src = x + (size_t)b * (L_ * C_) + (size_t)l0 * C_;
#pragma unroll
    for (int i = 0; i < 8; ++i) {
        int f = (i * 256 + t) * 4;                // flat (l,c) float index
        float4 v = *(const float4*)(src + f);
        int l = f >> 5, c = f & 31;
        float* d = &tile[l * 33 + c];
        d[0] = v.x; d[1] = v.y; d[2] = v.z; d[3] = v.w;
    }
    __syncthreads();
    const int c = t & 31, j = t >> 5;             // 8 threads per c-row
    const int ls = j << 5;                        // 32 l's per thread
    unsigned int pk[16];
#pragma unroll
    for (int i = 0; i < 16; ++i) {
        unsigned short a = f2bf(tile[(ls + 2 * i) * 33 + c]);
        unsigned short b2 = f2bf(tile[(ls + 2 * i + 1) * 33 + c]);
        pk[i] = (unsigned int)a | ((unsigned int)b2 << 16);
    }
    unsigned short* dst = xT + (size_t)b * (C_ * L_) + (size_t)c * L_ + l0 + ls;
    uint4* d4 = (uint4*)dst;
#pragma unroll
    for (int k = 0; k < 4; ++k) {
        uint4 q; q.x = pk[4 * k]; q.y = pk[4 * k + 1]; q.z = pk[4 * k + 2]; q.w = pk[4 * k + 3];
        d4[k] = q;
    }
}

// ---------------- pre-pass 2: W_pos fp32 -> bf16 ----------------
__global__ __launch_bounds__(256) void k_convert_wpos(const float* __restrict__ wp,
                                                      unsigned short* __restrict__ wpb) {
    const size_t i = ((size_t)blockIdx.x * 256 + threadIdx.x) * 8;
    float4 v0 = *(const float4*)(wp + i);
    float4 v1 = *(const float4*)(wp + i + 4);
    uint4 q;
    q.x = (unsigned)f2bf(v0.x) | ((unsigned)f2bf(v0.y) << 16);
    q.y = (unsigned)f2bf(v0.z) | ((unsigned)f2bf(v0.w) << 16);
    q.z = (unsigned)f2bf(v1.x) | ((unsigned)f2bf(v1.y) << 16);
    q.w = (unsigned)f2bf(v1.z) | ((unsigned)f2bf(v1.w) << 16);
    *(uint4*)(wpb + i) = q;
}

// ---------------- main fused GEMM ----------------
// A = xT (32768 x 2048 bf16 row-major, rows r = b*32+c), B^T = W_pos bf16 (2048 x 2048)
// epilogue: out[b,o] = sum_c Wc[o,c] * t[(b,c),o]
__global__ __launch_bounds__(256) void k_gemm(const unsigned short* __restrict__ A,
                                              const unsigned short* __restrict__ Wp,
                                              const float* __restrict__ Wc,
                                              float* __restrict__ out) {
    __shared__ unsigned short As[128 * 64];
    __shared__ unsigned short Bs[128 * 64];
    const int mt = blockIdx.x >> 4;               // 256 m-tiles
    const int nt = blockIdx.x & 15;               // 16 n-tiles
    const int t = threadIdx.x;
    const int lane = t & 63;
    const int w = t >> 6;
    const int rowBase = mt << 7;
    const int colBase = nt << 7;

    const int srow = w * 8 + (lane >> 3);         // staging row within 32-row chunk
    const int kg = lane & 7;                      // dest kgroup (8 bf16 each)
    const int kgsA = (kg ^ (srow & 7)) * 8;       // swizzled source kgroup offset (elems)

    const unsigned short* pa[4];
    const unsigned short* pb[4];
#pragma unroll
    for (int i = 0; i < 4; ++i) {
        pa[i] = A  + (size_t)(rowBase + i * 32 + srow) * 2048 + kgsA;
        pb[i] = Wp + (size_t)(colBase + i * 32 + srow) * 2048 + kgsA;
    }
    char* lA = (char*)As + w * 1024;
    char* lB = (char*)Bs + w * 1024;

    f32x4 acc[4][4] = {};

    const int wm = w >> 1, wn = w & 1;
    const int quad = lane >> 4, c16 = lane & 15;

    for (int kt = 0; kt < 32; ++kt) {
        const int k0 = kt * 64;
#pragma unroll
        for (int i = 0; i < 4; ++i) {
            async16(pa[i] + k0, lA + i * 4096);
            async16(pb[i] + k0, lB + i * 4096);
        }
        __syncthreads();                          // drains vmcnt + barrier
#pragma unroll
        for (int ks = 0; ks < 2; ++ks) {
            bf16x8 af[4], bfr[4];
#pragma unroll
            for (int mi = 0; mi < 4; ++mi) {
                int r = wm * 64 + mi * 16 + c16;
                af[mi] = *(const bf16x8*)((const char*)As + r * 128 + (((ks << 2) | quad) ^ (r & 7)) * 16);
                int cl = wn * 64 + mi * 16 + c16;
                bfr[mi] = *(const bf16x8*)((const char*)Bs + cl * 128 + (((ks << 2) | quad) ^ (cl & 7)) * 16);
            }
#pragma unroll
            for (int mi = 0; mi < 4; ++mi)
#pragma unroll
                for (int ni = 0; ni < 4; ++ni)
                    acc[mi][ni] = __builtin_amdgcn_mfma_f32_16x16x32_bf16(af[mi], bfr[ni], acc[mi][ni], 0, 0, 0);
        }
        __syncthreads();                          // protect LDS before next stage
    }

    // ---- epilogue: weighted c-reduction, write out[b, o] ----
    const int ob = colBase + wn * 64;
#pragma unroll
    for (int j = 0; j < 2; ++j) {                 // 2 b's per wave
        const int bg = (mt << 2) + (wm << 1) + j;
#pragma unroll
        for (int ni = 0; ni < 4; ++ni) {
            const int o = ob + ni * 16 + c16;
            const f32x4 w0 = *(const f32x4*)(Wc + o * 32 + quad * 4);        // c = quad*4..+3
            const f32x4 w1 = *(const f32x4*)(Wc + o * 32 + 16 + quad * 4);   // c = 16+quad*4..+3
            const f32x4 aA = acc[2 * j][ni];
            const f32x4 aB = acc[2 * j + 1][ni];
            float s = aA[0] * w0[0] + aA[1] * w0[1] + aA[2] * w0[2] + aA[3] * w0[3]
                    + aB[0] * w1[0] + aB[1] * w1[1] + aB[2] * w1[2] + aB[3] * w1[3];
            s += __shfl_xor(s, 16, 64);
            s += __shfl_xor(s, 32, 64);
            if (quad == 0) out[(size_t)bg * O_ + o] = s;
        }
    }
}

// ---------------- fallback (only if ws too small): fp32 VALU, slow but correct ----------------
__global__ __launch_bounds__(256) void k_fallback(const float* __restrict__ x,
                                                  const float* __restrict__ wpos,
                                                  const float* __restrict__ wchan,
                                                  float* __restrict__ out) {
    __shared__ float xs[128 * 32];
    const int b = blockIdx.x >> 3;
    const int o = ((blockIdx.x & 7) << 8) + threadIdx.x;
    float wc[32];
#pragma unroll
    for (int c = 0; c < 32; ++c) wc[c] = wchan[o * 32 + c];
    float acc = 0.f;
    for (int l0 = 0; l0 < 2048; l0 += 128) {
        __syncthreads();
#pragma unroll
        for (int i = 0; i < 16; ++i) {
            int f = i * 256 + threadIdx.x;
            xs[f] = x[(size_t)b * 65536 + (size_t)l0 * 32 + f];
        }
        __syncthreads();
        for (int l = 0; l < 128; ++l) {
            float wp = wpos[(size_t)o * 2048 + l0 + l];
            float s = 0.f;
#pragma unroll
            for (int c = 0; c < 32; ++c) s += xs[l * 32 + c] * wc[c];
            acc += wp * s;
        }
    }
    out[(size_t)b * 2048 + o] = acc;
}

extern "C" void kernel_launch(void* const* d_in, const int* in_sizes, int n_in,
                              void* d_out, int out_size, void* d_ws, size_t ws_size,
                              hipStream_t stream) {
    const float* x     = (const float*)d_in[0];
    const float* wpos  = (const float*)d_in[1];
    const float* wchan = (const float*)d_in[2];
    float* out = (float*)d_out;

    const size_t xT_bytes = (size_t)B_ * C_ * L_ * 2;   // 128 MiB
    const size_t wp_bytes = (size_t)O_ * L_ * 2;        // 8 MiB

    if (ws_size >= xT_bytes + wp_bytes) {
        unsigned short* xT  = (unsigned short*)d_ws;
        unsigned short* wpb = (unsigned short*)((char*)d_ws + xT_bytes);
        k_transpose_x<<<B_ * 8, 256, 0, stream>>>(x, xT);
        k_convert_wpos<<<(O_ * L_) / (256 * 8), 256, 0, stream>>>(wpos, wpb);
        k_gemm<<<(B_ * C_ / 128) * (O_ / 128), 256, 0, stream>>>(xT, wpb, wchan, out);
    } else {
        k_fallback<<<B_ * 8, 256, 0, stream>>>(x, wpos, wchan, out);
    }
}

// Round 2
// 669.519 us; speedup vs baseline: 1.0072x; 1.0072x over previous
//
#include <hip/hip_runtime.h>
#include <hip/hip_bf16.h>

#define B_ 1024
#define L_ 2048
#define C_ 32
#define O_ 2048

typedef short bf16x8 __attribute__((ext_vector_type(8)));
typedef float f32x4 __attribute__((ext_vector_type(4)));

__device__ __forceinline__ unsigned int f2bf(float f) {
    union { float f; unsigned int u; } v; v.f = f;
    unsigned int r = v.u + (0x7fffu + ((v.u >> 16) & 1u));
    return r >> 16;
}

__device__ __forceinline__ void async16(const void* g, const void* l) {
    __builtin_amdgcn_global_load_lds(
        (const __attribute__((address_space(1))) unsigned int*)g,
        (__attribute__((address_space(3))) unsigned int*)l, 16, 0, 0);
}

// ---------------- fused pre-pass ----------------
// blocks [0, 8192):   x (B,L,C) fp32 -> xT (B,C,L) bf16, LDS-free coalesced transpose
// blocks [8192, 10240): W_pos fp32 -> bf16
__global__ __launch_bounds__(256) void k_prep(const float* __restrict__ x,
                                              unsigned short* __restrict__ xT,
                                              const float* __restrict__ wp,
                                              unsigned short* __restrict__ wpb) {
    const int t = threadIdx.x;
    if (blockIdx.x < 8192) {
        const int b  = blockIdx.x >> 3;
        const int l0 = (blockIdx.x & 7) << 8;       // 256-l chunk
        const int c  = t & 31;
        const int lb = l0 + ((t >> 5) << 5);        // this thread's 32-l run
        // reads: per iteration, lanes (c=0..31) cover one contiguous 128B row -> coalesced
        const float* src = x + (size_t)b * (L_ * C_) + (size_t)lb * C_ + c;
        unsigned int pk[16];
#pragma unroll
        for (int i = 0; i < 16; ++i) {
            float a  = src[(2 * i)     * C_];
            float b2 = src[(2 * i + 1) * C_];
            pk[i] = f2bf(a) | (f2bf(b2) << 16);
        }
        // write: 64B contiguous per lane into xT[b, c, lb..lb+31]
        uint4* d4 = (uint4*)(xT + (size_t)b * (C_ * L_) + (size_t)c * L_ + lb);
#pragma unroll
        for (int k = 0; k < 4; ++k) {
            uint4 q; q.x = pk[4 * k]; q.y = pk[4 * k + 1]; q.z = pk[4 * k + 2]; q.w = pk[4 * k + 3];
            d4[k] = q;
        }
    } else {
        const size_t i = ((size_t)(blockIdx.x - 8192) * 256 + t) * 8;
        float4 v0 = *(const float4*)(wp + i);
        float4 v1 = *(const float4*)(wp + i + 4);
        uint4 q;
        q.x = f2bf(v0.x) | (f2bf(v0.y) << 16);
        q.y = f2bf(v0.z) | (f2bf(v0.w) << 16);
        q.z = f2bf(v1.x) | (f2bf(v1.y) << 16);
        q.w = f2bf(v1.z) | (f2bf(v1.w) << 16);
        *(uint4*)(wpb + i) = q;
    }
}

// ---------------- main fused GEMM ----------------
// A = xT (32768 x 2048 bf16 row-major, rows r = b*32+c), B^T = W_pos bf16 (2048 x 2048)
// epilogue: out[b,o] = sum_c Wc[o,c] * t[(b,c),o]
__global__ __launch_bounds__(256) void k_gemm(const unsigned short* __restrict__ A,
                                              const unsigned short* __restrict__ Wp,
                                              const float* __restrict__ Wc,
                                              float* __restrict__ out) {
    __shared__ unsigned short As[128 * 64];
    __shared__ unsigned short Bs[128 * 64];
    const int mt = blockIdx.x >> 4;               // 256 m-tiles
    const int nt = blockIdx.x & 15;               // 16 n-tiles
    const int t = threadIdx.x;
    const int lane = t & 63;
    const int w = t >> 6;
    const int rowBase = mt << 7;
    const int colBase = nt << 7;

    const int srow = w * 8 + (lane >> 3);         // staging row within 32-row chunk
    const int kg = lane & 7;                      // dest kgroup (8 bf16 each)
    const int kgsA = (kg ^ (srow & 7)) * 8;       // swizzled source kgroup offset (elems)

    const unsigned short* pa[4];
    const unsigned short* pb[4];
#pragma unroll
    for (int i = 0; i < 4; ++i) {
        pa[i] = A  + (size_t)(rowBase + i * 32 + srow) * 2048 + kgsA;
        pb[i] = Wp + (size_t)(colBase + i * 32 + srow) * 2048 + kgsA;
    }
    char* lA = (char*)As + w * 1024;
    char* lB = (char*)Bs + w * 1024;

    f32x4 acc[4][4] = {};

    const int wm = w >> 1, wn = w & 1;
    const int quad = lane >> 4, c16 = lane & 15;

    for (int kt = 0; kt < 32; ++kt) {
        const int k0 = kt * 64;
#pragma unroll
        for (int i = 0; i < 4; ++i) {
            async16(pa[i] + k0, lA + i * 4096);
            async16(pb[i] + k0, lB + i * 4096);
        }
        __syncthreads();                          // drains vmcnt + barrier
#pragma unroll
        for (int ks = 0; ks < 2; ++ks) {
            bf16x8 af[4], bfr[4];
#pragma unroll
            for (int mi = 0; mi < 4; ++mi) {
                int r = wm * 64 + mi * 16 + c16;
                af[mi] = *(const bf16x8*)((const char*)As + r * 128 + (((ks << 2) | quad) ^ (r & 7)) * 16);
                int cl = wn * 64 + mi * 16 + c16;
                bfr[mi] = *(const bf16x8*)((const char*)Bs + cl * 128 + (((ks << 2) | quad) ^ (cl & 7)) * 16);
            }
#pragma unroll
            for (int mi = 0; mi < 4; ++mi)
#pragma unroll
                for (int ni = 0; ni < 4; ++ni)
                    acc[mi][ni] = __builtin_amdgcn_mfma_f32_16x16x32_bf16(af[mi], bfr[ni], acc[mi][ni], 0, 0, 0);
        }
        __syncthreads();                          // protect LDS before next stage
    }

    // ---- epilogue: weighted c-reduction, write out[b, o] ----
    const int ob = colBase + wn * 64;
#pragma unroll
    for (int j = 0; j < 2; ++j) {                 // 2 b's per wave
        const int bg = (mt << 2) + (wm << 1) + j;
#pragma unroll
        for (int ni = 0; ni < 4; ++ni) {
            const int o = ob + ni * 16 + c16;
            const f32x4 w0 = *(const f32x4*)(Wc + o * 32 + quad * 4);        // c = quad*4..+3
            const f32x4 w1 = *(const f32x4*)(Wc + o * 32 + 16 + quad * 4);   // c = 16+quad*4..+3
            const f32x4 aA = acc[2 * j][ni];
            const f32x4 aB = acc[2 * j + 1][ni];
            float s = aA[0] * w0[0] + aA[1] * w0[1] + aA[2] * w0[2] + aA[3] * w0[3]
                    + aB[0] * w1[0] + aB[1] * w1[1] + aB[2] * w1[2] + aB[3] * w1[3];
            s += __shfl_xor(s, 16, 64);
            s += __shfl_xor(s, 32, 64);
            if (quad == 0) out[(size_t)bg * O_ + o] = s;
        }
    }
}

// ---------------- fallback (only if ws too small): fp32 VALU, slow but correct ----------------
__global__ __launch_bounds__(256) void k_fallback(const float* __restrict__ x,
                                                  const float* __restrict__ wpos,
                                                  const float* __restrict__ wchan,
                                                  float* __restrict__ out) {
    __shared__ float xs[128 * 32];
    const int b = blockIdx.x >> 3;
    const int o = ((blockIdx.x & 7) << 8) + threadIdx.x;
    float wc[32];
#pragma unroll
    for (int c = 0; c < 32; ++c) wc[c] = wchan[o * 32 + c];
    float acc = 0.f;
    for (int l0 = 0; l0 < 2048; l0 += 128) {
        __syncthreads();
#pragma unroll
        for (int i = 0; i < 16; ++i) {
            int f = i * 256 + threadIdx.x;
            xs[f] = x[(size_t)b * 65536 + (size_t)l0 * 32 + f];
        }
        __syncthreads();
        for (int l = 0; l < 128; ++l) {
            float wp = wpos[(size_t)o * 2048 + l0 + l];
            float s = 0.f;
#pragma unroll
            for (int c = 0; c < 32; ++c) s += xs[l * 32 + c] * wc[c];
            acc += wp * s;
        }
    }
    out[(size_t)b * 2048 + o] = acc;
}

extern "C" void kernel_launch(void* const* d_in, const int* in_sizes, int n_in,
                              void* d_out, int out_size, void* d_ws, size_t ws_size,
                              hipStream_t stream) {
    const float* x     = (const float*)d_in[0];
    const float* wpos  = (const float*)d_in[1];
    const float* wchan = (const float*)d_in[2];
    float* out = (float*)d_out;

    const size_t xT_bytes = (size_t)B_ * C_ * L_ * 2;   // 128 MiB
    const size_t wp_bytes = (size_t)O_ * L_ * 2;        // 8 MiB

    if (ws_size >= xT_bytes + wp_bytes) {
        unsigned short* xT  = (unsigned short*)d_ws;
        unsigned short* wpb = (unsigned short*)((char*)d_ws + xT_bytes);
        k_prep<<<8192 + 2048, 256, 0, stream>>>(x, xT, wpos, wpb);
        k_gemm<<<(B_ * C_ / 128) * (O_ / 128), 256, 0, stream>>>(xT, wpb, wchan, out);
    } else {
        k_fallback<<<B_ * 8, 256, 0, stream>>>(x, wpos, wchan, out);
    }
}